// Round 2
// baseline (329.985 us; speedup 1.0000x reference)
//
#include <hip/hip_runtime.h>

using short8 = __attribute__((ext_vector_type(8))) short;
using f32x4  = __attribute__((ext_vector_type(4))) float;

__device__ __forceinline__ short b16(float f) {
  __bf16 h = (__bf16)f;
  return __builtin_bit_cast(short, h);
}

__device__ __forceinline__ short8 pack8(const float4& a, const float4& b) {
  short8 r;
  r[0] = b16(a.x); r[1] = b16(a.y); r[2] = b16(a.z); r[3] = b16(a.w);
  r[4] = b16(b.x); r[5] = b16(b.y); r[6] = b16(b.z); r[7] = b16(b.w);
  return r;
}

// Kernel 1: W' = softmax(weight_mat / softplus(tau), axis=-1) * 0.125
// (the 1/sqrt(64) score scale is folded in here). One block per row.
__global__ __launch_bounds__(256) void w_softmax_kernel(
    const float* __restrict__ wm, const float* __restrict__ tau,
    float* __restrict__ wout) {
  const int row = blockIdx.x;
  const int tid = threadIdx.x;
  const float sp  = log1pf(__expf(tau[row]));
  const float inv = 1.0f / sp;
  const float4* src = (const float4*)(wm + (size_t)row * 1024);
  float4 v = src[tid];
  float v0 = v.x * inv, v1 = v.y * inv, v2 = v.z * inv, v3 = v.w * inv;
  float mx = fmaxf(fmaxf(v0, v1), fmaxf(v2, v3));
  #pragma unroll
  for (int m = 1; m < 64; m <<= 1) mx = fmaxf(mx, __shfl_xor(mx, m));
  __shared__ float red[8];
  const int wv = tid >> 6;
  if ((tid & 63) == 0) red[wv] = mx;
  __syncthreads();
  mx = fmaxf(fmaxf(red[0], red[1]), fmaxf(red[2], red[3]));
  float e0 = __expf(v0 - mx), e1 = __expf(v1 - mx);
  float e2 = __expf(v2 - mx), e3 = __expf(v3 - mx);
  float s = e0 + e1 + e2 + e3;
  #pragma unroll
  for (int m = 1; m < 64; m <<= 1) s += __shfl_xor(s, m);
  if ((tid & 63) == 0) red[4 + wv] = s;
  __syncthreads();
  s = red[4] + red[5] + red[6] + red[7];
  const float r = 0.125f / s;   // fold QK^T scale 1/8 into w'
  float4* dst = (float4*)(wout + (size_t)row * 1024);
  float4 o; o.x = e0 * r; o.y = e1 * r; o.z = e2 * r; o.w = e3 * r;
  dst[tid] = o;
}

// Kernel 2: flash attention with per-(q,s) multiplicative modulation w'.
// Block = 256 threads (4 waves), one (b,h), 64 q rows; KV tiles of 64.
// Pipelined: tile t+1's K/V/w are loaded into registers during tile t.
__global__ __launch_bounds__(256, 4) void attn_kernel(
    const float* __restrict__ Q, const float* __restrict__ K,
    const float* __restrict__ V, const float* __restrict__ W,
    float* __restrict__ O) {
  const int bid = blockIdx.x;
  const int qt = bid & 15;        // q-tile fastest: consecutive blocks share K/V
  const int h  = (bid >> 4) & 7;
  const int b  = bid >> 7;
  const int q0 = qt * 64;

  const int tid  = threadIdx.x;
  const int wv   = tid >> 6;
  const int lane = tid & 63;
  const int lc   = lane & 15;
  const int g    = lane >> 4;

  __shared__ alignas(16) short Ks[64 * 64];   // K tile, row s, swizzle (s&7)<<4
  __shared__ alignas(16) short Vt[64 * 64];   // V^T tile, row d, swizzle ((d&7)^(d>>3))<<4
  __shared__ alignas(16) char Pl[4 * 2336];   // per-wave P, row off = r*144 + (r>>3)<<5

  // Q A-fragments: m = lc (q row), k = ks*32 + g*8 + j
  const int qg_frag = q0 + wv * 16 + lc;
  const float* qptr = Q + ((size_t)(b * 1024 + qg_frag)) * 512 + h * 64;
  short8 aQ[2];
  #pragma unroll
  for (int ks = 0; ks < 2; ++ks) {
    float4 f0 = *(const float4*)(qptr + ks * 32 + g * 8);
    float4 f1 = *(const float4*)(qptr + ks * 32 + g * 8 + 4);
    aQ[ks] = pack8(f0, f1);
  }

  // staging assignment: 4 threads per row, 16 contiguous floats each
  const int s_loc = tid >> 2;        // 0..63
  const int cb    = (tid & 3) * 16;  // 0,16,32,48
  const float* kp0 = K + ((size_t)(b * 1024 + s_loc)) * 512 + h * 64 + cb;
  const float* vp0 = V + ((size_t)(b * 1024 + s_loc)) * 512 + h * 64 + cb;

  // ---- prefetch tile 0 into registers ----
  float4 kx0 = *(const float4*)(kp0);
  float4 kx1 = *(const float4*)(kp0 + 4);
  float4 kx2 = *(const float4*)(kp0 + 8);
  float4 kx3 = *(const float4*)(kp0 + 12);
  float4 vx0 = *(const float4*)(vp0);
  float4 vx1 = *(const float4*)(vp0 + 4);
  float4 vx2 = *(const float4*)(vp0 + 8);
  float4 vx3 = *(const float4*)(vp0 + 12);

  // w' registers for tile 0: wreg[r*4+n] = W'[q0+wv*16+g*4+r][n*16+lc]
  const float* wb = W + (size_t)(q0 + wv * 16 + g * 4) * 1024 + lc;
  float wreg[16];
  #pragma unroll
  for (int r = 0; r < 4; ++r)
    #pragma unroll
    for (int n = 0; n < 4; ++n)
      wreg[r * 4 + n] = wb[(size_t)r * 1024 + n * 16];

  f32x4 o[4];
  #pragma unroll
  for (int n = 0; n < 4; ++n) o[n] = (f32x4){0.f, 0.f, 0.f, 0.f};
  float m_r[4] = {-INFINITY, -INFINITY, -INFINITY, -INFINITY};
  float l_r[4] = {0.f, 0.f, 0.f, 0.f};

  char* pw = Pl + wv * 2336;

  #pragma unroll 1
  for (int kt = 0; kt < 16; ++kt) {
    __syncthreads();  // previous tile fully consumed
    {   // stage K tile regs -> bf16 LDS, swizzled
      const int sw = (s_loc & 7) << 4;
      char* kb = (char*)Ks + s_loc * 128;
      *(short8*)(kb + ((cb * 2) ^ sw))      = pack8(kx0, kx1);
      *(short8*)(kb + ((cb * 2 + 16) ^ sw)) = pack8(kx2, kx3);
    }
    {   // stage V tile transposed -> Vt[d][s], cb-spread swizzle
      float va[16] = {vx0.x, vx0.y, vx0.z, vx0.w, vx1.x, vx1.y, vx1.z, vx1.w,
                      vx2.x, vx2.y, vx2.z, vx2.w, vx3.x, vx3.y, vx3.z, vx3.w};
      #pragma unroll
      for (int j = 0; j < 16; ++j) {
        const int d = cb + j;
        const int swv = (((d & 7) ^ (d >> 3)) & 7) << 4;
        *(short*)((char*)Vt + d * 128 + ((s_loc * 2) ^ swv)) = b16(va[j]);
      }
    }
    // ---- issue next tile's K/V loads (latency hides under compute) ----
    {
      const int soff = (((kt + 1) & 15) * 64) * 512;
      kx0 = *(const float4*)(kp0 + soff);
      kx1 = *(const float4*)(kp0 + soff + 4);
      kx2 = *(const float4*)(kp0 + soff + 8);
      kx3 = *(const float4*)(kp0 + soff + 12);
      vx0 = *(const float4*)(vp0 + soff);
      vx1 = *(const float4*)(vp0 + soff + 4);
      vx2 = *(const float4*)(vp0 + soff + 8);
      vx3 = *(const float4*)(vp0 + soff + 12);
    }
    __syncthreads();

    // ---- S = Q K^T (per wave: 16 q x 64 s) ----
    f32x4 sacc[4];
    #pragma unroll
    for (int n = 0; n < 4; ++n) {
      const int srow = n * 16 + lc;
      const int swz  = (srow & 7) << 4;
      const char* kb = (const char*)Ks + srow * 128;
      short8 b0 = *(const short8*)(kb + ((g * 16) ^ swz));
      short8 b1 = *(const short8*)(kb + ((64 + g * 16) ^ swz));
      f32x4 z = (f32x4){0.f, 0.f, 0.f, 0.f};
      z = __builtin_amdgcn_mfma_f32_16x16x32_bf16(aQ[0], b0, z, 0, 0, 0);
      z = __builtin_amdgcn_mfma_f32_16x16x32_bf16(aQ[1], b1, z, 0, 0, 0);
      sacc[n] = z;
    }

    // ---- modulation + online softmax; p overwrites sacc ----
    #pragma unroll
    for (int r = 0; r < 4; ++r) {
      float lg[4];
      #pragma unroll
      for (int n = 0; n < 4; ++n) lg[n] = sacc[n][r] * wreg[r * 4 + n];
      float tmax = fmaxf(fmaxf(lg[0], lg[1]), fmaxf(lg[2], lg[3]));
      #pragma unroll
      for (int msk = 1; msk < 16; msk <<= 1)
        tmax = fmaxf(tmax, __shfl_xor(tmax, msk));
      const float mnew = fmaxf(m_r[r], tmax);
      const float corr = __expf(m_r[r] - mnew);
      m_r[r] = mnew;
      float rs = 0.f;
      #pragma unroll
      for (int n = 0; n < 4; ++n) {
        const float e = __expf(lg[n] - mnew);
        sacc[n][r] = e;
        rs += e;
      }
      #pragma unroll
      for (int msk = 1; msk < 16; msk <<= 1) rs += __shfl_xor(rs, msk);
      l_r[r] = l_r[r] * corr + rs;
      #pragma unroll
      for (int n = 0; n < 4; ++n) o[n][r] *= corr;
    }

    // ---- reload w' for next tile (after last use; hides under PV) ----
    {
      const int s0n = ((kt + 1) & 15) * 64;
      #pragma unroll
      for (int r = 0; r < 4; ++r)
        #pragma unroll
        for (int n = 0; n < 4; ++n)
          wreg[r * 4 + n] = wb[(size_t)r * 1024 + s0n + n * 16];
    }

    // ---- P -> per-wave LDS (bf16, conflict-free rows), then PV ----
    #pragma unroll
    for (int r = 0; r < 4; ++r) {
      const int row = g * 4 + r;
      const int off = row * 144 + ((row >> 3) << 5);
      #pragma unroll
      for (int n = 0; n < 4; ++n)
        *(short*)(pw + off + (n * 16 + lc) * 2) = b16(sacc[n][r]);
    }

    const char* pb = pw + lc * 144 + ((lc >> 3) << 5);
    short8 aP0 = *(const short8*)(pb + g * 16);
    short8 aP1 = *(const short8*)(pb + 64 + g * 16);
    #pragma unroll
    for (int n = 0; n < 4; ++n) {
      const int drow = n * 16 + lc;
      const int swv  = (((drow & 7) ^ (drow >> 3)) & 7) << 4;
      const char* vbp = (const char*)Vt + drow * 128;
      short8 b0 = *(const short8*)(vbp + ((g * 16) ^ swv));
      short8 b1 = *(const short8*)(vbp + ((64 + g * 16) ^ swv));
      o[n] = __builtin_amdgcn_mfma_f32_16x16x32_bf16(aP0, b0, o[n], 0, 0, 0);
      o[n] = __builtin_amdgcn_mfma_f32_16x16x32_bf16(aP1, b1, o[n], 0, 0, 0);
    }
  }

  // ---- epilogue: O / l ----
  #pragma unroll
  for (int r = 0; r < 4; ++r) {
    const float invl = 1.0f / l_r[r];
    const int qg = q0 + wv * 16 + g * 4 + r;
    float* op = O + ((size_t)(b * 1024 + qg)) * 512 + h * 64 + lc;
    #pragma unroll
    for (int n = 0; n < 4; ++n) op[n * 16] = o[n][r] * invl;
  }
}

extern "C" void kernel_launch(void* const* d_in, const int* in_sizes, int n_in,
                              void* d_out, int out_size, void* d_ws, size_t ws_size,
                              hipStream_t stream) {
  const float* Q   = (const float*)d_in[0];
  const float* K   = (const float*)d_in[1];
  const float* V   = (const float*)d_in[2];
  const float* WM  = (const float*)d_in[3];
  const float* TAU = (const float*)d_in[4];
  float* Wbuf = (float*)d_ws;           // 1024*1024*4 = 4 MB scratch
  float* out  = (float*)d_out;

  w_softmax_kernel<<<dim3(1024), dim3(256), 0, stream>>>(WM, TAU, Wbuf);
  attn_kernel<<<dim3(16 * 8 * 16), dim3(256), 0, stream>>>(Q, K, V, Wbuf, out);
}

// Round 3
// 309.523 us; speedup vs baseline: 1.0661x; 1.0661x over previous
//
#include <hip/hip_runtime.h>

using short8 = __attribute__((ext_vector_type(8))) short;
using f32x4  = __attribute__((ext_vector_type(4))) float;

__device__ __forceinline__ short b16(float f) {
  __bf16 h = (__bf16)f;
  return __builtin_bit_cast(short, h);
}

__device__ __forceinline__ short8 pack8(const float4& a, const float4& b) {
  short8 r;
  r[0] = b16(a.x); r[1] = b16(a.y); r[2] = b16(a.z); r[3] = b16(a.w);
  r[4] = b16(b.x); r[5] = b16(b.y); r[6] = b16(b.z); r[7] = b16(b.w);
  return r;
}

// Kernel 1: W' = softmax(weight_mat / softplus(tau), axis=-1) * 0.125
__global__ __launch_bounds__(256) void w_softmax_kernel(
    const float* __restrict__ wm, const float* __restrict__ tau,
    float* __restrict__ wout) {
  const int row = blockIdx.x;
  const int tid = threadIdx.x;
  const float sp  = log1pf(__expf(tau[row]));
  const float inv = 1.0f / sp;
  const float4* src = (const float4*)(wm + (size_t)row * 1024);
  float4 v = src[tid];
  float v0 = v.x * inv, v1 = v.y * inv, v2 = v.z * inv, v3 = v.w * inv;
  float mx = fmaxf(fmaxf(v0, v1), fmaxf(v2, v3));
  #pragma unroll
  for (int m = 1; m < 64; m <<= 1) mx = fmaxf(mx, __shfl_xor(mx, m));
  __shared__ float red[8];
  const int wv = tid >> 6;
  if ((tid & 63) == 0) red[wv] = mx;
  __syncthreads();
  mx = fmaxf(fmaxf(red[0], red[1]), fmaxf(red[2], red[3]));
  float e0 = __expf(v0 - mx), e1 = __expf(v1 - mx);
  float e2 = __expf(v2 - mx), e3 = __expf(v3 - mx);
  float s = e0 + e1 + e2 + e3;
  #pragma unroll
  for (int m = 1; m < 64; m <<= 1) s += __shfl_xor(s, m);
  if ((tid & 63) == 0) red[4 + wv] = s;
  __syncthreads();
  s = red[4] + red[5] + red[6] + red[7];
  const float r = 0.125f / s;
  float4* dst = (float4*)(wout + (size_t)row * 1024);
  float4 o; o.x = e0 * r; o.y = e1 * r; o.z = e2 * r; o.w = e3 * r;
  dst[tid] = o;
}

// Kernel 2: flash attention, modulation w'. 4 waves, 64 q rows/block,
// KV tiles of 64, LDS double-buffered, ONE barrier per tile.
__global__ __launch_bounds__(256, 3) void attn_kernel(
    const float* __restrict__ Q, const float* __restrict__ K,
    const float* __restrict__ V, const float* __restrict__ W,
    float* __restrict__ O) {
  // T1: XCD-bijective swizzle (2048 blocks, 8 XCDs -> 256 per XCD).
  // Blocks sharing (b,h) (consecutive qt) land on the same XCD's L2.
  const int orig = blockIdx.x;
  const int bid  = (orig & 7) * 256 + (orig >> 3);
  const int qt = bid & 15;
  const int h  = (bid >> 4) & 7;
  const int b  = bid >> 7;
  const int q0 = qt * 64;

  const int tid  = threadIdx.x;
  const int wv   = tid >> 6;
  const int lane = tid & 63;
  const int lc   = lane & 15;
  const int g    = lane >> 4;

  __shared__ alignas(16) short Ks[2][4096];   // swizzle (s&7)<<4
  __shared__ alignas(16) short Vt[2][4096];   // swizzle ((d&7)^(d>>3))<<4
  __shared__ alignas(16) char Pl[4 * 2336];   // row off = r*144 + (r>>3)<<5

  // Q A-fragments
  const int qg_frag = q0 + wv * 16 + lc;
  const float* qptr = Q + ((size_t)(b * 1024 + qg_frag)) * 512 + h * 64;
  short8 aQ[2];
  #pragma unroll
  for (int ks = 0; ks < 2; ++ks) {
    float4 f0 = *(const float4*)(qptr + ks * 32 + g * 8);
    float4 f1 = *(const float4*)(qptr + ks * 32 + g * 8 + 4);
    aQ[ks] = pack8(f0, f1);
  }

  const int s_loc = tid >> 2;        // 0..63
  const int cb    = (tid & 3) * 16;  // 0,16,32,48
  const float* kp0 = K + ((size_t)(b * 1024 + s_loc)) * 512 + h * 64 + cb;
  const float* vp0 = V + ((size_t)(b * 1024 + s_loc)) * 512 + h * 64 + cb;
  const int swK = (s_loc & 7) << 4;

  // w' regs for tile 0
  const float* wb = W + (size_t)(q0 + wv * 16 + g * 4) * 1024 + lc;
  float wreg[16];
  #pragma unroll
  for (int r = 0; r < 4; ++r)
    #pragma unroll
    for (int n = 0; n < 4; ++n)
      wreg[r * 4 + n] = wb[(size_t)r * 1024 + n * 16];

  // ---- prologue: stage tile 0 into buffer 0 ----
  {
    float4 a0 = *(const float4*)(kp0);
    float4 a1 = *(const float4*)(kp0 + 4);
    float4 a2 = *(const float4*)(kp0 + 8);
    float4 a3 = *(const float4*)(kp0 + 12);
    float4 c0 = *(const float4*)(vp0);
    float4 c1 = *(const float4*)(vp0 + 4);
    float4 c2 = *(const float4*)(vp0 + 8);
    float4 c3 = *(const float4*)(vp0 + 12);
    char* kb = (char*)Ks[0] + s_loc * 128;
    *(short8*)(kb + ((cb * 2) ^ swK))      = pack8(a0, a1);
    *(short8*)(kb + ((cb * 2 + 16) ^ swK)) = pack8(a2, a3);
    float va[16] = {c0.x, c0.y, c0.z, c0.w, c1.x, c1.y, c1.z, c1.w,
                    c2.x, c2.y, c2.z, c2.w, c3.x, c3.y, c3.z, c3.w};
    #pragma unroll
    for (int j = 0; j < 16; ++j) {
      const int d = cb + j;
      const int swv = (((d & 7) ^ (d >> 3)) & 7) << 4;
      *(short*)((char*)Vt[0] + d * 128 + ((s_loc * 2) ^ swv)) = b16(va[j]);
    }
  }
  __syncthreads();

  f32x4 o[4];
  #pragma unroll
  for (int n = 0; n < 4; ++n) o[n] = (f32x4){0.f, 0.f, 0.f, 0.f};
  float m_r[4] = {-INFINITY, -INFINITY, -INFINITY, -INFINITY};
  float l_r[4] = {0.f, 0.f, 0.f, 0.f};

  char* pw = Pl + wv * 2336;

  #pragma unroll 2
  for (int kt = 0; kt < 16; ++kt) {
    const int c = kt & 1;
    // ---- issue next-tile loads FIRST (consumed at bottom; latency hides
    // under the whole compute phase). kt==15 re-reads tile 15 (L2-hot).
    const int ktn = (kt < 15) ? (kt + 1) : 15;
    const size_t soff = (size_t)(ktn * 64) * 512;
    float4 nk0 = *(const float4*)(kp0 + soff);
    float4 nk1 = *(const float4*)(kp0 + soff + 4);
    float4 nk2 = *(const float4*)(kp0 + soff + 8);
    float4 nk3 = *(const float4*)(kp0 + soff + 12);
    float4 nv0 = *(const float4*)(vp0 + soff);
    float4 nv1 = *(const float4*)(vp0 + soff + 4);
    float4 nv2 = *(const float4*)(vp0 + soff + 8);
    float4 nv3 = *(const float4*)(vp0 + soff + 12);
    __builtin_amdgcn_sched_barrier(0);   // pin the load issue above compute

    // ---- S = Q K^T from Ks[c] ----
    f32x4 sacc[4];
    #pragma unroll
    for (int n = 0; n < 4; ++n) {
      const int srow = n * 16 + lc;
      const int swz  = (srow & 7) << 4;
      const char* kb = (const char*)Ks[c] + srow * 128;
      short8 b0 = *(const short8*)(kb + ((g * 16) ^ swz));
      short8 b1 = *(const short8*)(kb + ((64 + g * 16) ^ swz));
      f32x4 z = (f32x4){0.f, 0.f, 0.f, 0.f};
      z = __builtin_amdgcn_mfma_f32_16x16x32_bf16(aQ[0], b0, z, 0, 0, 0);
      z = __builtin_amdgcn_mfma_f32_16x16x32_bf16(aQ[1], b1, z, 0, 0, 0);
      sacc[n] = z;
    }

    // ---- modulation + online softmax; p overwrites sacc ----
    #pragma unroll
    for (int r = 0; r < 4; ++r) {
      float lg[4];
      #pragma unroll
      for (int n = 0; n < 4; ++n) lg[n] = sacc[n][r] * wreg[r * 4 + n];
      float tmax = fmaxf(fmaxf(lg[0], lg[1]), fmaxf(lg[2], lg[3]));
      #pragma unroll
      for (int msk = 1; msk < 16; msk <<= 1)
        tmax = fmaxf(tmax, __shfl_xor(tmax, msk));
      const float mnew = fmaxf(m_r[r], tmax);
      const float corr = __expf(m_r[r] - mnew);
      m_r[r] = mnew;
      float rs = 0.f;
      #pragma unroll
      for (int n = 0; n < 4; ++n) {
        const float e = __expf(lg[n] - mnew);
        sacc[n][r] = e;
        rs += e;
      }
      #pragma unroll
      for (int msk = 1; msk < 16; msk <<= 1) rs += __shfl_xor(rs, msk);
      l_r[r] = l_r[r] * corr + rs;
      #pragma unroll
      for (int n = 0; n < 4; ++n) o[n][r] *= corr;
    }

    // ---- reload w' for next tile (hides under PV) ----
    if (kt < 15) {
      const int s0n = (kt + 1) * 64;
      #pragma unroll
      for (int r = 0; r < 4; ++r)
        #pragma unroll
        for (int n = 0; n < 4; ++n)
          wreg[r * 4 + n] = wb[(size_t)r * 1024 + s0n + n * 16];
    }

    // ---- P -> per-wave LDS, then PV from Vt[c] ----
    #pragma unroll
    for (int r = 0; r < 4; ++r) {
      const int row = g * 4 + r;
      const int off = row * 144 + ((row >> 3) << 5);
      #pragma unroll
      for (int n = 0; n < 4; ++n)
        *(short*)(pw + off + (n * 16 + lc) * 2) = b16(sacc[n][r]);
    }

    const char* pb = pw + lc * 144 + ((lc >> 3) << 5);
    short8 aP0 = *(const short8*)(pb + g * 16);
    short8 aP1 = *(const short8*)(pb + 64 + g * 16);
    #pragma unroll
    for (int n = 0; n < 4; ++n) {
      const int drow = n * 16 + lc;
      const int swv  = (((drow & 7) ^ (drow >> 3)) & 7) << 4;
      const char* vbp = (const char*)Vt[c] + drow * 128;
      short8 b0 = *(const short8*)(vbp + ((g * 16) ^ swv));
      short8 b1 = *(const short8*)(vbp + ((64 + g * 16) ^ swv));
      o[n] = __builtin_amdgcn_mfma_f32_16x16x32_bf16(aP0, b0, o[n], 0, 0, 0);
      o[n] = __builtin_amdgcn_mfma_f32_16x16x32_bf16(aP1, b1, o[n], 0, 0, 0);
    }

    // ---- write next tile into the other buffer; ONE barrier per tile ----
    if (kt < 15) {
      char* kb = (char*)Ks[c ^ 1] + s_loc * 128;
      *(short8*)(kb + ((cb * 2) ^ swK))      = pack8(nk0, nk1);
      *(short8*)(kb + ((cb * 2 + 16) ^ swK)) = pack8(nk2, nk3);
      float va[16] = {nv0.x, nv0.y, nv0.z, nv0.w, nv1.x, nv1.y, nv1.z, nv1.w,
                      nv2.x, nv2.y, nv2.z, nv2.w, nv3.x, nv3.y, nv3.z, nv3.w};
      #pragma unroll
      for (int j = 0; j < 16; ++j) {
        const int d = cb + j;
        const int swv = (((d & 7) ^ (d >> 3)) & 7) << 4;
        *(short*)((char*)Vt[c ^ 1] + d * 128 + ((s_loc * 2) ^ swv)) = b16(va[j]);
      }
    }
    __syncthreads();
  }

  // ---- epilogue: O / l ----
  #pragma unroll
  for (int r = 0; r < 4; ++r) {
    const float invl = 1.0f / l_r[r];
    const int qg = q0 + wv * 16 + g * 4 + r;
    float* op = O + ((size_t)(b * 1024 + qg)) * 512 + h * 64 + lc;
    #pragma unroll
    for (int n = 0; n < 4; ++n) op[n * 16] = o[n][r] * invl;
  }
}

extern "C" void kernel_launch(void* const* d_in, const int* in_sizes, int n_in,
                              void* d_out, int out_size, void* d_ws, size_t ws_size,
                              hipStream_t stream) {
  const float* Q   = (const float*)d_in[0];
  const float* K   = (const float*)d_in[1];
  const float* V   = (const float*)d_in[2];
  const float* WM  = (const float*)d_in[3];
  const float* TAU = (const float*)d_in[4];
  float* Wbuf = (float*)d_ws;           // 4 MB scratch
  float* out  = (float*)d_out;

  w_softmax_kernel<<<dim3(1024), dim3(256), 0, stream>>>(WM, TAU, Wbuf);
  attn_kernel<<<dim3(16 * 8 * 16), dim3(256), 0, stream>>>(Q, K, V, Wbuf, out);
}

// Round 4
// 254.687 us; speedup vs baseline: 1.2957x; 1.2153x over previous
//
#include <hip/hip_runtime.h>

using short8 = __attribute__((ext_vector_type(8))) short;
using f32x16 = __attribute__((ext_vector_type(16))) float;

__device__ __forceinline__ short b16(float f) {
  __bf16 h = (__bf16)f;
  return __builtin_bit_cast(short, h);
}
__device__ __forceinline__ short8 pack8(const float4& a, const float4& b) {
  short8 r;
  r[0] = b16(a.x); r[1] = b16(a.y); r[2] = b16(a.z); r[3] = b16(a.w);
  r[4] = b16(b.x); r[5] = b16(b.y); r[6] = b16(b.z); r[7] = b16(b.w);
  return r;
}
__device__ __forceinline__ unsigned pk2(float lo, float hi) {
  return ((unsigned)(unsigned short)b16(hi) << 16) | (unsigned)(unsigned short)b16(lo);
}

// Kernel 1: W' = softmax(weight_mat / softplus(tau), axis=-1) * 0.125
__global__ __launch_bounds__(256) void w_softmax_kernel(
    const float* __restrict__ wm, const float* __restrict__ tau,
    float* __restrict__ wout) {
  const int row = blockIdx.x;
  const int tid = threadIdx.x;
  const float sp  = log1pf(__expf(tau[row]));
  const float inv = 1.0f / sp;
  const float4* src = (const float4*)(wm + (size_t)row * 1024);
  float4 v = src[tid];
  float v0 = v.x * inv, v1 = v.y * inv, v2 = v.z * inv, v3 = v.w * inv;
  float mx = fmaxf(fmaxf(v0, v1), fmaxf(v2, v3));
  #pragma unroll
  for (int m = 1; m < 64; m <<= 1) mx = fmaxf(mx, __shfl_xor(mx, m));
  __shared__ float red[8];
  const int wv = tid >> 6;
  if ((tid & 63) == 0) red[wv] = mx;
  __syncthreads();
  mx = fmaxf(fmaxf(red[0], red[1]), fmaxf(red[2], red[3]));
  float e0 = __expf(v0 - mx), e1 = __expf(v1 - mx);
  float e2 = __expf(v2 - mx), e3 = __expf(v3 - mx);
  float s = e0 + e1 + e2 + e3;
  #pragma unroll
  for (int m = 1; m < 64; m <<= 1) s += __shfl_xor(s, m);
  if ((tid & 63) == 0) red[4 + wv] = s;
  __syncthreads();
  s = red[4] + red[5] + red[6] + red[7];
  const float r = 0.125f / s;
  float4* dst = (float4*)(wout + (size_t)row * 1024);
  float4 o; o.x = e0 * r; o.y = e1 * r; o.z = e2 * r; o.w = e3 * r;
  dst[tid] = o;
}

// Kernel 2: 32x32 swapped-QK flash attention. 4 waves x 32 q-rows = 128 q/block.
// S^T = mfma(K,Q): lane holds S[s][q=lane&31] for 32 s-values -> lane-local softmax.
__global__ __launch_bounds__(256, 2) void attn_kernel(
    const float* __restrict__ Q, const float* __restrict__ K,
    const float* __restrict__ V, const float* __restrict__ W,
    float* __restrict__ O) {
  const int orig = blockIdx.x;                 // 1024 blocks
  const int bid  = (orig & 7) * 128 + (orig >> 3);   // XCD-bijective: XCD x <- qblk x
  const int qblk = bid >> 7;                   // 0..7 (128 q rows each)
  const int bh   = bid & 127;
  const int b = bh >> 3, h = bh & 7;

  const int tid = threadIdx.x, wv = tid >> 6, lane = tid & 63;
  const int ql = lane & 31, hi = lane >> 5;
  const int qg = qblk * 128 + wv * 32 + ql;    // this lane's q row (global in L)

  __shared__ alignas(16) short Ks[2][4096];    // K tile [s][e] bf16, swz (s&7)<<4
  __shared__ alignas(16) short Vt[2][4096];    // V^T tile [d][s] bf16, swz ((d&7)^(d>>3))<<4
  __shared__ float Sc[128];                    // per-wave broadcast scratch [wv*32+q]

  // ---- Q B-fragments: B[k=e][n=q]: lane ql=q, k = es*16 + hi*8 + j ----
  const float* qrow = Q + ((size_t)(b * 1024 + qg)) * 512 + h * 64;
  short8 qb[4];
  #pragma unroll
  for (int es = 0; es < 4; ++es) {
    float4 f0 = *(const float4*)(qrow + es * 16 + hi * 8);
    float4 f1 = *(const float4*)(qrow + es * 16 + hi * 8 + 4);
    qb[es] = pack8(f0, f1);
  }

  // ---- staging assignment: thread -> K/V row srow, 16 float cols at cgrp ----
  const int srow = tid >> 2;          // 0..63
  const int cgrp = (tid & 3) * 16;    // 0,16,32,48
  const float* kp = K + ((size_t)(b * 1024 + srow)) * 512 + h * 64 + cgrp;
  const float* vp = V + ((size_t)(b * 1024 + srow)) * 512 + h * 64 + cgrp;
  const int kswz = (srow & 7) << 4;
  const int kwb0 = srow * 128 + ((cgrp * 2) ^ kswz);
  const int kwb1 = srow * 128 + ((cgrp * 2 + 16) ^ kswz);

  // ---- prologue: stage tile 0 into buffer 0 ----
  {
    float4 a0 = *(const float4*)(kp);
    float4 a1 = *(const float4*)(kp + 4);
    float4 a2 = *(const float4*)(kp + 8);
    float4 a3 = *(const float4*)(kp + 12);
    float4 c0 = *(const float4*)(vp);
    float4 c1 = *(const float4*)(vp + 4);
    float4 c2 = *(const float4*)(vp + 8);
    float4 c3 = *(const float4*)(vp + 12);
    *(short8*)((char*)Ks[0] + kwb0) = pack8(a0, a1);
    *(short8*)((char*)Ks[0] + kwb1) = pack8(a2, a3);
    float va[16] = {c0.x, c0.y, c0.z, c0.w, c1.x, c1.y, c1.z, c1.w,
                    c2.x, c2.y, c2.z, c2.w, c3.x, c3.y, c3.z, c3.w};
    #pragma unroll
    for (int j = 0; j < 16; ++j) {
      const int d = cgrp + j;
      const int vswz = (((d & 7) ^ (d >> 3)) & 7) << 4;
      *(short*)((char*)Vt[0] + d * 128 + ((srow * 2) ^ vswz)) = b16(va[j]);
    }
  }
  __syncthreads();

  f32x16 o0, o1;
  #pragma unroll
  for (int i = 0; i < 16; ++i) { o0[i] = 0.f; o1[i] = 0.f; }
  float m_r = -INFINITY, l_r = 0.f;

  const float* wr = W + (size_t)qg * 1024;   // this lane's W' row

  #pragma unroll 1
  for (int kt = 0; kt < 16; ++kt) {
    const int c = kt & 1;
    const int s0 = kt * 64;

    // ---- T14: issue next-tile K/V global loads now, consume at bottom ----
    float4 nk0, nk1, nk2, nk3, nv0, nv1, nv2, nv3;
    if (kt < 15) {
      const size_t soff = (size_t)((kt + 1) * 64) * 512;
      nk0 = *(const float4*)(kp + soff);      nk1 = *(const float4*)(kp + soff + 4);
      nk2 = *(const float4*)(kp + soff + 8);  nk3 = *(const float4*)(kp + soff + 12);
      nv0 = *(const float4*)(vp + soff);      nv1 = *(const float4*)(vp + soff + 4);
      nv2 = *(const float4*)(vp + soff + 8);  nv3 = *(const float4*)(vp + soff + 12);
    }

    // ---- w' loads for this tile: wreg[st*16 + rg*4 + c] matches p-index ----
    float wreg[32];
    #pragma unroll
    for (int st = 0; st < 2; ++st)
      #pragma unroll
      for (int rg = 0; rg < 4; ++rg) {
        float4 t = *(const float4*)(wr + s0 + st * 32 + rg * 8 + hi * 4);
        wreg[st * 16 + rg * 4 + 0] = t.x;
        wreg[st * 16 + rg * 4 + 1] = t.y;
        wreg[st * 16 + rg * 4 + 2] = t.z;
        wreg[st * 16 + rg * 4 + 3] = t.w;
      }

    // ---- S^T = mfma(K, Q): lane holds S[s][q=ql], s = st*32 + crow(reg,hi) ----
    f32x16 sa0, sa1;
    #pragma unroll
    for (int i = 0; i < 16; ++i) { sa0[i] = 0.f; sa1[i] = 0.f; }
    {
      const int sr0 = ql, sr1 = 32 + ql;
      const char* kb0 = (const char*)Ks[c] + sr0 * 128;
      const char* kb1 = (const char*)Ks[c] + sr1 * 128;
      const int sz0 = (sr0 & 7) << 4, sz1 = (sr1 & 7) << 4;
      #pragma unroll
      for (int es = 0; es < 4; ++es) {
        short8 ka0 = *(const short8*)(kb0 + ((es * 32 + hi * 16) ^ sz0));
        short8 ka1 = *(const short8*)(kb1 + ((es * 32 + hi * 16) ^ sz1));
        sa0 = __builtin_amdgcn_mfma_f32_32x32x16_bf16(ka0, qb[es], sa0, 0, 0, 0);
        sa1 = __builtin_amdgcn_mfma_f32_32x32x16_bf16(ka1, qb[es], sa1, 0, 0, 0);
      }
    }

    // ---- logits = S * w' ----
    float lg[32];
    #pragma unroll
    for (int reg = 0; reg < 16; ++reg) {
      lg[reg]      = sa0[reg] * wreg[reg];
      lg[16 + reg] = sa1[reg] * wreg[16 + reg];
    }

    // ---- max: in-register tree + one cross-half shfl ----
    float t16[16];
    #pragma unroll
    for (int i = 0; i < 16; ++i) t16[i] = fmaxf(lg[i], lg[i + 16]);
    float t8[8];
    #pragma unroll
    for (int i = 0; i < 8; ++i) t8[i] = fmaxf(t16[i], t16[i + 8]);
    float t4[4];
    #pragma unroll
    for (int i = 0; i < 4; ++i) t4[i] = fmaxf(t8[i], t8[i + 4]);
    float pmax = fmaxf(fmaxf(t4[0], t4[1]), fmaxf(t4[2], t4[3]));
    pmax = fmaxf(pmax, __shfl_xor(pmax, 32));

    // ---- T13 defer-max: rescale only if max grew by > 8 ----
    if (!__all(pmax <= m_r + 8.0f)) {
      const float mnew = fmaxf(m_r, pmax);
      const float corr = __expf(m_r - mnew);
      m_r = mnew;
      l_r *= corr;
      if (lane < 32) Sc[wv * 32 + ql] = corr;
      #pragma unroll
      for (int reg = 0; reg < 16; ++reg) {
        const float cr = Sc[wv * 32 + ((reg & 3) + 8 * (reg >> 2) + 4 * hi)];
        o0[reg] *= cr; o1[reg] *= cr;
      }
    }

    // ---- p = exp(lg - m), rowsum via tree + one shfl ----
    float p[32];
    #pragma unroll
    for (int i = 0; i < 32; ++i) p[i] = __expf(lg[i] - m_r);
    float s16[16];
    #pragma unroll
    for (int i = 0; i < 16; ++i) s16[i] = p[i] + p[i + 16];
    float s8[8];
    #pragma unroll
    for (int i = 0; i < 8; ++i) s8[i] = s16[i] + s16[i + 8];
    float s4[4];
    #pragma unroll
    for (int i = 0; i < 4; ++i) s4[i] = s8[i] + s8[i + 4];
    float rs = (s4[0] + s4[1]) + (s4[2] + s4[3]);
    rs += __shfl_xor(rs, 32);
    l_r += rs;

    // ---- P -> bf16 A-fragments (pack pairs + cross-half exchange) ----
    unsigned cc[16];
    #pragma unroll
    for (int t = 0; t < 16; ++t) cc[t] = pk2(p[2 * t], p[2 * t + 1]);
    short8 pa[4];
    #pragma unroll
    for (int ks = 0; ks < 4; ++ks) {
      unsigned snd0 = hi ? cc[4 * ks]     : cc[4 * ks + 2];
      unsigned snd1 = hi ? cc[4 * ks + 1] : cc[4 * ks + 3];
      unsigned e0 = __shfl_xor(snd0, 32);
      unsigned e1 = __shfl_xor(snd1, 32);
      uint4 dw;
      dw.x = hi ? e0 : cc[4 * ks];
      dw.y = hi ? e1 : cc[4 * ks + 1];
      dw.z = hi ? cc[4 * ks + 2] : e0;
      dw.w = hi ? cc[4 * ks + 3] : e1;
      pa[ks] = __builtin_bit_cast(short8, dw);
    }

    // ---- O += P V : B-frag from Vt[c] ----
    #pragma unroll
    for (int nt = 0; nt < 2; ++nt) {
      const int d = nt * 32 + ql;
      const char* vb = (const char*)Vt[c] + d * 128;
      const int vswz = (((d & 7) ^ (d >> 3)) & 7) << 4;
      #pragma unroll
      for (int ks = 0; ks < 4; ++ks) {
        short8 bf = *(const short8*)(vb + ((ks * 32 + hi * 16) ^ vswz));
        if (nt == 0) o0 = __builtin_amdgcn_mfma_f32_32x32x16_bf16(pa[ks], bf, o0, 0, 0, 0);
        else         o1 = __builtin_amdgcn_mfma_f32_32x32x16_bf16(pa[ks], bf, o1, 0, 0, 0);
      }
    }

    // ---- stage next tile into buffer c^1; ONE barrier per tile ----
    if (kt < 15) {
      *(short8*)((char*)Ks[c ^ 1] + kwb0) = pack8(nk0, nk1);
      *(short8*)((char*)Ks[c ^ 1] + kwb1) = pack8(nk2, nk3);
      float va[16] = {nv0.x, nv0.y, nv0.z, nv0.w, nv1.x, nv1.y, nv1.z, nv1.w,
                      nv2.x, nv2.y, nv2.z, nv2.w, nv3.x, nv3.y, nv3.z, nv3.w};
      #pragma unroll
      for (int j = 0; j < 16; ++j) {
        const int d = cgrp + j;
        const int vswz = (((d & 7) ^ (d >> 3)) & 7) << 4;
        *(short*)((char*)Vt[c ^ 1] + d * 128 + ((srow * 2) ^ vswz)) = b16(va[j]);
      }
    }
    __syncthreads();
  }

  // ---- epilogue: broadcast l per output row, divide, store ----
  if (lane < 32) Sc[wv * 32 + ql] = l_r;
  #pragma unroll
  for (int reg = 0; reg < 16; ++reg) {
    const int qq = (reg & 3) + 8 * (reg >> 2) + 4 * hi;   // output q row (local)
    const float lv = Sc[wv * 32 + qq];
    const float inv = 1.0f / lv;
    float* op = O + ((size_t)(b * 1024 + qblk * 128 + wv * 32 + qq)) * 512 + h * 64 + ql;
    op[0]  = o0[reg] * inv;
    op[32] = o1[reg] * inv;
  }
}

extern "C" void kernel_launch(void* const* d_in, const int* in_sizes, int n_in,
                              void* d_out, int out_size, void* d_ws, size_t ws_size,
                              hipStream_t stream) {
  const float* Q   = (const float*)d_in[0];
  const float* K   = (const float*)d_in[1];
  const float* V   = (const float*)d_in[2];
  const float* WM  = (const float*)d_in[3];
  const float* TAU = (const float*)d_in[4];
  float* Wbuf = (float*)d_ws;           // 4 MB scratch
  float* out  = (float*)d_out;

  w_softmax_kernel<<<dim3(1024), dim3(256), 0, stream>>>(WM, TAU, Wbuf);
  attn_kernel<<<dim3(1024), dim3(256), 0, stream>>>(Q, K, V, Wbuf, out);
}

// Round 5
// 234.223 us; speedup vs baseline: 1.4089x; 1.0874x over previous
//
#include <hip/hip_runtime.h>

using short8 = __attribute__((ext_vector_type(8))) short;
using f32x16 = __attribute__((ext_vector_type(16))) float;

__device__ __forceinline__ short b16(float f) {
  __bf16 h = (__bf16)f;
  return __builtin_bit_cast(short, h);
}
__device__ __forceinline__ short8 pack8(const float4& a, const float4& b) {
  short8 r;
  r[0] = b16(a.x); r[1] = b16(a.y); r[2] = b16(a.z); r[3] = b16(a.w);
  r[4] = b16(b.x); r[5] = b16(b.y); r[6] = b16(b.z); r[7] = b16(b.w);
  return r;
}
__device__ __forceinline__ unsigned pk2(float lo, float hi) {
  return ((unsigned)(unsigned short)b16(hi) << 16) | (unsigned)(unsigned short)b16(lo);
}
__device__ __forceinline__ float bf2f(unsigned short u) {
  return __builtin_bit_cast(float, ((unsigned)u) << 16);
}

// Kernel 1: W' = softmax(weight_mat / softplus(tau)) * 0.125, bf16 out (row-major)
__global__ __launch_bounds__(256) void w_softmax_kernel(
    const float* __restrict__ wm, const float* __restrict__ tau,
    unsigned short* __restrict__ wout) {
  const int row = blockIdx.x;
  const int tid = threadIdx.x;
  const float sp  = log1pf(__expf(tau[row]));
  const float inv = 1.0f / sp;
  const float4* src = (const float4*)(wm + (size_t)row * 1024);
  float4 v = src[tid];
  float v0 = v.x * inv, v1 = v.y * inv, v2 = v.z * inv, v3 = v.w * inv;
  float mx = fmaxf(fmaxf(v0, v1), fmaxf(v2, v3));
  #pragma unroll
  for (int m = 1; m < 64; m <<= 1) mx = fmaxf(mx, __shfl_xor(mx, m));
  __shared__ float red[8];
  const int wv = tid >> 6;
  if ((tid & 63) == 0) red[wv] = mx;
  __syncthreads();
  mx = fmaxf(fmaxf(red[0], red[1]), fmaxf(red[2], red[3]));
  float e0 = __expf(v0 - mx), e1 = __expf(v1 - mx);
  float e2 = __expf(v2 - mx), e3 = __expf(v3 - mx);
  float s = e0 + e1 + e2 + e3;
  #pragma unroll
  for (int m = 1; m < 64; m <<= 1) s += __shfl_xor(s, m);
  if ((tid & 63) == 0) red[4 + wv] = s;
  __syncthreads();
  s = red[4] + red[5] + red[6] + red[7];
  const float r = 0.125f / s;
  ushort4 o;
  o.x = (unsigned short)b16(e0 * r); o.y = (unsigned short)b16(e1 * r);
  o.z = (unsigned short)b16(e2 * r); o.w = (unsigned short)b16(e3 * r);
  *(ushort4*)(wout + (size_t)row * 1024 + tid * 4) = o;
}

// Kernel 2: transpose bf16 W' (row-major [q][s]) -> Wt [s][q]. 64x64 tiles.
__global__ __launch_bounds__(256) void w_transpose_kernel(
    const unsigned short* __restrict__ win, unsigned short* __restrict__ wt) {
  __shared__ unsigned short tile[64][73];   // pad 73: column reads conflict-free
  const int ti = blockIdx.x & 15;   // s-tile
  const int tj = blockIdx.x >> 4;   // q-tile
  const int t  = threadIdx.x;
  const int qa = t >> 2;            // 0..63
  const int sb = (t & 3) * 16;      // 0,16,32,48
  const unsigned short* src = win + (size_t)(tj * 64 + qa) * 1024 + ti * 64 + sb;
  short8 a0 = *(const short8*)(src);
  short8 a1 = *(const short8*)(src + 8);
  #pragma unroll
  for (int j = 0; j < 8; ++j) { tile[qa][sb + j] = a0[j]; tile[qa][sb + 8 + j] = a1[j]; }
  __syncthreads();
  const int sr = t >> 2;            // local s row to write
  const int qb = (t & 3) * 16;      // local q chunk
  short8 w0, w1;
  #pragma unroll
  for (int j = 0; j < 8; ++j) { w0[j] = tile[qb + j][sr]; w1[j] = tile[qb + 8 + j][sr]; }
  unsigned short* dst = wt + (size_t)(ti * 64 + sr) * 1024 + tj * 64 + qb;
  *(short8*)(dst) = w0;
  *(short8*)(dst + 8) = w1;
}

// Kernel 3: 32x32 swapped-QK flash attention. 4 waves x 32 q-rows = 128 q/block.
__global__ __launch_bounds__(256, 2) void attn_kernel(
    const float* __restrict__ Q, const float* __restrict__ K,
    const float* __restrict__ V, const unsigned short* __restrict__ Wt,
    float* __restrict__ O) {
  // XCD-bijective swizzle: the 8 qblk-blocks sharing one (b,h) land on ONE
  // XCD with consecutive slots (L2 reuse of K/V).
  const int orig = blockIdx.x;                 // 1024 blocks
  const int xcd  = orig & 7, slot = orig >> 3; // slot 0..127
  const int bh   = xcd * 16 + (slot >> 3);     // 0..127
  const int qblk = slot & 7;                   // 0..7
  const int b = bh >> 3, h = bh & 7;

  const int tid = threadIdx.x, wv = tid >> 6, lane = tid & 63;
  const int ql = lane & 31, hi = lane >> 5;
  const int qg = qblk * 128 + wv * 32 + ql;    // this lane's q row

  __shared__ alignas(16) short Ks[2][4096];    // K tile [s][e] bf16, swz (s&7)<<4
  __shared__ alignas(16) short Vt[2][4096];    // V^T tile [d][s] bf16, swz ((d&7)^(d>>3))<<4
  __shared__ float Sc[128];                    // per-wave broadcast scratch

  // Q B-fragments: lane ql = q, k = es*16 + hi*8 + j
  const float* qrow = Q + ((size_t)(b * 1024 + qg)) * 512 + h * 64;
  short8 qb[4];
  #pragma unroll
  for (int es = 0; es < 4; ++es) {
    float4 f0 = *(const float4*)(qrow + es * 16 + hi * 8);
    float4 f1 = *(const float4*)(qrow + es * 16 + hi * 8 + 4);
    qb[es] = pack8(f0, f1);
  }

  // staging: thread -> K/V row srow, 16 float cols at cgrp
  const int srow = tid >> 2;
  const int cgrp = (tid & 3) * 16;
  const float* kp = K + ((size_t)(b * 1024 + srow)) * 512 + h * 64 + cgrp;
  const float* vp = V + ((size_t)(b * 1024 + srow)) * 512 + h * 64 + cgrp;
  const int kswz = (srow & 7) << 4;
  const int kwb0 = srow * 128 + ((cgrp * 2) ^ kswz);
  const int kwb1 = srow * 128 + ((cgrp * 2 + 16) ^ kswz);

  {   // prologue: stage tile 0 into buffer 0
    float4 a0 = *(const float4*)(kp);
    float4 a1 = *(const float4*)(kp + 4);
    float4 a2 = *(const float4*)(kp + 8);
    float4 a3 = *(const float4*)(kp + 12);
    float4 c0 = *(const float4*)(vp);
    float4 c1 = *(const float4*)(vp + 4);
    float4 c2 = *(const float4*)(vp + 8);
    float4 c3 = *(const float4*)(vp + 12);
    *(short8*)((char*)Ks[0] + kwb0) = pack8(a0, a1);
    *(short8*)((char*)Ks[0] + kwb1) = pack8(a2, a3);
    float va[16] = {c0.x, c0.y, c0.z, c0.w, c1.x, c1.y, c1.z, c1.w,
                    c2.x, c2.y, c2.z, c2.w, c3.x, c3.y, c3.z, c3.w};
    #pragma unroll
    for (int j = 0; j < 16; ++j) {
      const int d = cgrp + j;
      const int vswz = (((d & 7) ^ (d >> 3)) & 7) << 4;
      *(short*)((char*)Vt[0] + d * 128 + ((srow * 2) ^ vswz)) = b16(va[j]);
    }
  }
  __syncthreads();

  f32x16 o0, o1;
  #pragma unroll
  for (int i = 0; i < 16; ++i) { o0[i] = 0.f; o1[i] = 0.f; }
  float m_r = -INFINITY, l_r = 0.f;

  const unsigned short* wcol = Wt + qg;   // lane's q column of Wt[s][q]

  #pragma unroll 1
  for (int kt = 0; kt < 16; ++kt) {
    const int c = kt & 1;
    const int s0 = kt * 64;

    // ---- T14: issue next-tile K/V global loads now, consume at bottom ----
    float4 nk0, nk1, nk2, nk3, nv0, nv1, nv2, nv3;
    if (kt < 15) {
      const size_t soff = (size_t)((kt + 1) * 64) * 512;
      nk0 = *(const float4*)(kp + soff);      nk1 = *(const float4*)(kp + soff + 4);
      nk2 = *(const float4*)(kp + soff + 8);  nk3 = *(const float4*)(kp + soff + 12);
      nv0 = *(const float4*)(vp + soff);      nv1 = *(const float4*)(vp + soff + 4);
      nv2 = *(const float4*)(vp + soff + 8);  nv3 = *(const float4*)(vp + soff + 12);
    }

    // ---- this tile's w: 32 coalesced ushort loads (hidden under QK MFMAs) ----
    // wreg[st*16 + rg*4 + cc] = Wt[s0 + st*32 + rg*8 + 4*hi + cc][qg]
    unsigned short wu[32];
    #pragma unroll
    for (int st = 0; st < 2; ++st)
      #pragma unroll
      for (int rg = 0; rg < 4; ++rg)
        #pragma unroll
        for (int cc = 0; cc < 4; ++cc)
          wu[st * 16 + rg * 4 + cc] =
              wcol[(size_t)(s0 + st * 32 + rg * 8 + 4 * hi + cc) * 1024];

    // ---- S^T = mfma(K, Q) ----
    f32x16 sa0, sa1;
    #pragma unroll
    for (int i = 0; i < 16; ++i) { sa0[i] = 0.f; sa1[i] = 0.f; }
    {
      const int sr0 = ql, sr1 = 32 + ql;
      const char* kb0 = (const char*)Ks[c] + sr0 * 128;
      const char* kb1 = (const char*)Ks[c] + sr1 * 128;
      const int sz0 = (sr0 & 7) << 4, sz1 = (sr1 & 7) << 4;
      __builtin_amdgcn_s_setprio(1);
      #pragma unroll
      for (int es = 0; es < 4; ++es) {
        short8 ka0 = *(const short8*)(kb0 + ((es * 32 + hi * 16) ^ sz0));
        short8 ka1 = *(const short8*)(kb1 + ((es * 32 + hi * 16) ^ sz1));
        sa0 = __builtin_amdgcn_mfma_f32_32x32x16_bf16(ka0, qb[es], sa0, 0, 0, 0);
        sa1 = __builtin_amdgcn_mfma_f32_32x32x16_bf16(ka1, qb[es], sa1, 0, 0, 0);
      }
      __builtin_amdgcn_s_setprio(0);
    }

    // ---- logits ----
    float lg[32];
    #pragma unroll
    for (int reg = 0; reg < 16; ++reg) {
      lg[reg]      = sa0[reg] * bf2f(wu[reg]);
      lg[16 + reg] = sa1[reg] * bf2f(wu[16 + reg]);
    }

    // ---- max: in-register tree + one cross-half shfl ----
    float t16[16];
    #pragma unroll
    for (int i = 0; i < 16; ++i) t16[i] = fmaxf(lg[i], lg[i + 16]);
    float t8[8];
    #pragma unroll
    for (int i = 0; i < 8; ++i) t8[i] = fmaxf(t16[i], t16[i + 8]);
    float t4[4];
    #pragma unroll
    for (int i = 0; i < 4; ++i) t4[i] = fmaxf(t8[i], t8[i + 4]);
    float pmax = fmaxf(fmaxf(t4[0], t4[1]), fmaxf(t4[2], t4[3]));
    pmax = fmaxf(pmax, __shfl_xor(pmax, 32));

    // ---- T13 defer-max ----
    if (!__all(pmax <= m_r + 8.0f)) {
      const float mnew = fmaxf(m_r, pmax);
      const float corr = __expf(m_r - mnew);
      m_r = mnew;
      l_r *= corr;
      if (lane < 32) Sc[wv * 32 + ql] = corr;
      #pragma unroll
      for (int reg = 0; reg < 16; ++reg) {
        const float cr = Sc[wv * 32 + ((reg & 3) + 8 * (reg >> 2) + 4 * hi)];
        o0[reg] *= cr; o1[reg] *= cr;
      }
    }

    // ---- p = exp, rowsum ----
    float p[32];
    #pragma unroll
    for (int i = 0; i < 32; ++i) p[i] = __expf(lg[i] - m_r);
    float s16[16];
    #pragma unroll
    for (int i = 0; i < 16; ++i) s16[i] = p[i] + p[i + 16];
    float s8[8];
    #pragma unroll
    for (int i = 0; i < 8; ++i) s8[i] = s16[i] + s16[i + 8];
    float s4[4];
    #pragma unroll
    for (int i = 0; i < 4; ++i) s4[i] = s8[i] + s8[i + 4];
    float rs = (s4[0] + s4[1]) + (s4[2] + s4[3]);
    rs += __shfl_xor(rs, 32);
    l_r += rs;

    // ---- P -> bf16 A-fragments ----
    unsigned cc16[16];
    #pragma unroll
    for (int t = 0; t < 16; ++t) cc16[t] = pk2(p[2 * t], p[2 * t + 1]);
    short8 pa[4];
    #pragma unroll
    for (int ks = 0; ks < 4; ++ks) {
      unsigned snd0 = hi ? cc16[4 * ks]     : cc16[4 * ks + 2];
      unsigned snd1 = hi ? cc16[4 * ks + 1] : cc16[4 * ks + 3];
      unsigned e0 = __shfl_xor(snd0, 32);
      unsigned e1 = __shfl_xor(snd1, 32);
      uint4 dw;
      dw.x = hi ? e0 : cc16[4 * ks];
      dw.y = hi ? e1 : cc16[4 * ks + 1];
      dw.z = hi ? cc16[4 * ks + 2] : e0;
      dw.w = hi ? cc16[4 * ks + 3] : e1;
      pa[ks] = __builtin_bit_cast(short8, dw);
    }

    // ---- O += P V ----
    __builtin_amdgcn_s_setprio(1);
    #pragma unroll
    for (int nt = 0; nt < 2; ++nt) {
      const int d = nt * 32 + ql;
      const char* vb = (const char*)Vt[c] + d * 128;
      const int vswz = (((d & 7) ^ (d >> 3)) & 7) << 4;
      #pragma unroll
      for (int ks = 0; ks < 4; ++ks) {
        short8 bf = *(const short8*)(vb + ((ks * 32 + hi * 16) ^ vswz));
        if (nt == 0) o0 = __builtin_amdgcn_mfma_f32_32x32x16_bf16(pa[ks], bf, o0, 0, 0, 0);
        else         o1 = __builtin_amdgcn_mfma_f32_32x32x16_bf16(pa[ks], bf, o1, 0, 0, 0);
      }
    }
    __builtin_amdgcn_s_setprio(0);

    // ---- stage next tile; ONE barrier per tile ----
    if (kt < 15) {
      *(short8*)((char*)Ks[c ^ 1] + kwb0) = pack8(nk0, nk1);
      *(short8*)((char*)Ks[c ^ 1] + kwb1) = pack8(nk2, nk3);
      float va[16] = {nv0.x, nv0.y, nv0.z, nv0.w, nv1.x, nv1.y, nv1.z, nv1.w,
                      nv2.x, nv2.y, nv2.z, nv2.w, nv3.x, nv3.y, nv3.z, nv3.w};
      #pragma unroll
      for (int j = 0; j < 16; ++j) {
        const int d = cgrp + j;
        const int vswz = (((d & 7) ^ (d >> 3)) & 7) << 4;
        *(short*)((char*)Vt[c ^ 1] + d * 128 + ((srow * 2) ^ vswz)) = b16(va[j]);
      }
    }
    __syncthreads();
  }

  // ---- epilogue ----
  if (lane < 32) Sc[wv * 32 + ql] = l_r;
  #pragma unroll
  for (int reg = 0; reg < 16; ++reg) {
    const int qq = (reg & 3) + 8 * (reg >> 2) + 4 * hi;
    const float lv = Sc[wv * 32 + qq];
    const float inv = 1.0f / lv;
    float* op = O + ((size_t)(b * 1024 + qblk * 128 + wv * 32 + qq)) * 512 + h * 64 + ql;
    op[0]  = o0[reg] * inv;
    op[32] = o1[reg] * inv;
  }
}

extern "C" void kernel_launch(void* const* d_in, const int* in_sizes, int n_in,
                              void* d_out, int out_size, void* d_ws, size_t ws_size,
                              hipStream_t stream) {
  const float* Q   = (const float*)d_in[0];
  const float* K   = (const float*)d_in[1];
  const float* V   = (const float*)d_in[2];
  const float* WM  = (const float*)d_in[3];
  const float* TAU = (const float*)d_in[4];
  unsigned short* Wrm = (unsigned short*)d_ws;                 // 2 MB bf16 row-major
  unsigned short* Wt  = (unsigned short*)((char*)d_ws + (1 << 21)); // 2 MB bf16 transposed
  float* out = (float*)d_out;

  w_softmax_kernel<<<dim3(1024), dim3(256), 0, stream>>>(WM, TAU, Wrm);
  w_transpose_kernel<<<dim3(256), dim3(256), 0, stream>>>(Wrm, Wt);
  attn_kernel<<<dim3(1024), dim3(256), 0, stream>>>(Q, K, V, Wt, out);
}